// Round 15
// baseline (9265.120 us; speedup 1.0000x reference)
//
#include <hip/hip_runtime.h>

#define TT 2048
#define HH 512
#define EE 512
#define NTAGS 48
#define G4 2048   // 4*HH
#define NWG 16    // workgroups per direction in the LSTM kernel
#define CANARY 1.0e30f

typedef float f4 __attribute__((ext_vector_type(4)));

// workspace byte offsets
#define OFF_XW    0ULL                                      // [2][TT][G4] f32 = 32 MB
#define OFF_HCAT  (OFF_XW   + 2ULL*TT*G4*4ULL)              // [TT][1024] f32 = 8 MB
#define OFF_FRM   (OFF_HCAT + (unsigned long long)TT*1024ULL*4ULL) // [TT][48] f32
#define OFF_HBUF  (OFF_FRM  + (unsigned long long)TT*NTAGS*4ULL)   // [2][4][HH] f32 (canary slots)
#define OFF_BP    (OFF_HBUF + 2ULL*4ULL*HH*4ULL)            // [TT][48] u8

// fast activations: v_exp_f32 + v_rcp_f32 (rel err ~1e-6; output threshold 106)
__device__ __forceinline__ float fsig(float x) {
    return __builtin_amdgcn_rcpf(1.f + __expf(-x));
}
__device__ __forceinline__ float ftanh(float x) {
    return 1.f - 2.f*__builtin_amdgcn_rcpf(__expf(2.f*x) + 1.f);
}

// ---------------------------------------------------------------------------
// K1: xW[dir][t][r] = sum_e embed[words[t]][e]*Wih[dir][r][e] + bih[r]+bhh[r]
// 64x64 tile, 256 threads, 4x4 micro-tile, K-chunk 32. Also canary-fills the
// LSTM h exchange slots. (unchanged)
// ---------------------------------------------------------------------------
__global__ __launch_bounds__(256) void k_xw(
    const int* __restrict__ words, const float* __restrict__ embed,
    const float* __restrict__ WihF, const float* __restrict__ WihB,
    const float* __restrict__ bihF, const float* __restrict__ bhhF,
    const float* __restrict__ bihB, const float* __restrict__ bhhB,
    float* __restrict__ xw, float* __restrict__ hbuf)
{
    const int tid = threadIdx.x;
    const int bx = blockIdx.x, by = blockIdx.y, dir = blockIdx.z;

    if (bx == 0 && by == 0) {                   // one block per dir: canary fill
        for (int j = tid; j < 4*HH; j += 256)
            hbuf[dir*4*HH + j] = CANARY;
    }

    const float* Wih = dir ? WihB : WihF;
    const float* bi  = dir ? bihB : bihF;
    const float* bh  = dir ? bhhB : bhhF;

    __shared__ float sa[32][64];
    __shared__ float sb[32][64];
    __shared__ int   wds[64];
    if (tid < 64) wds[tid] = words[by*64 + tid];
    const int tx = tid & 15, ty = tid >> 4;
    float acc[4][4] = {};
    __syncthreads();

    for (int k0 = 0; k0 < EE; k0 += 32) {
        #pragma unroll
        for (int u = 0; u < 2; u++) {
            int idx = tid*2 + u;            // 0..511
            int row = idx >> 3, kq = idx & 7;
            float4 av = *(const float4*)&embed[(size_t)wds[row]*EE + k0 + kq*4];
            float4 bv = *(const float4*)&Wih[(size_t)(bx*64 + row)*EE + k0 + kq*4];
            sa[kq*4+0][row] = av.x; sa[kq*4+1][row] = av.y;
            sa[kq*4+2][row] = av.z; sa[kq*4+3][row] = av.w;
            sb[kq*4+0][row] = bv.x; sb[kq*4+1][row] = bv.y;
            sb[kq*4+2][row] = bv.z; sb[kq*4+3][row] = bv.w;
        }
        __syncthreads();
        #pragma unroll
        for (int k = 0; k < 32; k++) {
            float4 a = *(const float4*)&sa[k][ty*4];
            float4 b = *(const float4*)&sb[k][tx*4];
            acc[0][0] += a.x*b.x; acc[0][1] += a.x*b.y; acc[0][2] += a.x*b.z; acc[0][3] += a.x*b.w;
            acc[1][0] += a.y*b.x; acc[1][1] += a.y*b.y; acc[1][2] += a.y*b.z; acc[1][3] += a.y*b.w;
            acc[2][0] += a.z*b.x; acc[2][1] += a.z*b.y; acc[2][2] += a.z*b.z; acc[2][3] += a.z*b.w;
            acc[3][0] += a.w*b.x; acc[3][1] += a.w*b.y; acc[3][2] += a.w*b.z; acc[3][3] += a.w*b.w;
        }
        __syncthreads();
    }

    float* outp = xw + (size_t)dir*TT*G4;
    const int rbase = bx*64 + tx*4;
    float4 bi4 = *(const float4*)&bi[rbase];
    float4 bh4 = *(const float4*)&bh[rbase];
    float4 bias = make_float4(bi4.x+bh4.x, bi4.y+bh4.y, bi4.z+bh4.z, bi4.w+bh4.w);
    #pragma unroll
    for (int i = 0; i < 4; i++) {
        int t = by*64 + ty*4 + i;
        float4 v = make_float4(acc[i][0]+bias.x, acc[i][1]+bias.y,
                               acc[i][2]+bias.z, acc[i][3]+bias.w);
        *(float4*)&outp[(size_t)t*G4 + rbase] = v;
    }
}

// ---------------------------------------------------------------------------
// K2: Bi-LSTM recurrence with DIRECT-TO-REGISTER h exchange (no LDS restage,
// ONE barrier/step). 16-way-split dot: thread (v,hi,k16) owns 4 gate-rows x
// one 32-float K-chunk (asm-opaque weights). Its dot input = its chunk =
// one contiguous 128B line of hb -> the consumer POLLS THAT LINE directly
// into the dot registers hvv[8] (8x dwordx4 sc1, vmcnt(0)+sched_barrier per
// rule #18, loop until all 32 non-canary; values are canary->h monotone so
// the first clean pass holds h). gv is parity-double-buffered: gv[p] written
// in step s is read by the producer before it reaches barrier A(s+1), and
// the next gv[p] write comes after A(s+1) -> WAR-safe with one barrier.
// Producer path + 4-slot canary rotation + R1 vmcnt ordering = proven R13.
// ---------------------------------------------------------------------------
__global__ __launch_bounds__(512, 2) void k_lstm(
    const float* __restrict__ WhhF, const float* __restrict__ WhhB,
    const float* __restrict__ h0, const float* __restrict__ c0,
    const float* __restrict__ xw,
    float* __restrict__ hbuf, float* __restrict__ hcat)
{
    const int bid = blockIdx.x;
    const int dir = bid >> 4;
    const int w   = bid & 15;
    const float* Whh = dir ? WhhB : WhhF;
    const float* xwD = xw + (size_t)dir*TT*G4;
    float* hb = hbuf + dir*4*HH;        // [slot][HH]

    const int tid  = threadIdx.x;
    const int v    = tid >> 6;          // wave 0..7
    const int l    = tid & 63;
    const int hi   = l >> 4;            // 0..3: wave's 4 h-outputs
    const int k16  = l & 15;            // K-chunk id (32 floats = 128B line)
    const int loc  = v*4 + hi;          // 0..31 local h index
    const int hidx = w*32 + loc;        // global h index [0,512)

    // weights: 4 gate-rows x own 32-float chunk, asm-opaque (128 VGPR)
    f4 wreg[4][8];
    {
        #pragma unroll
        for (int g = 0; g < 4; g++) {
            const f4* wr = (const f4*)&Whh[(size_t)(g*HH + hidx)*HH + k16*32];
            #pragma unroll
            for (int t = 0; t < 8; t++)
                asm volatile("global_load_dwordx4 %0, %1, off"
                             : "=v"(wreg[g][t]) : "v"(wr + t));
        }
        asm volatile("s_waitcnt vmcnt(0)" ::: "memory");
        __builtin_amdgcn_sched_barrier(0);      // rule #18
    }
    float c = 0.f;
    if (tid < 32) c = c0[dir*HH + w*32 + tid];

    __shared__ float gv[2][128];        // parity-double-buffered gate sums

    // initial h chunk -> registers (h0 is always valid, no canary)
    f4 hvv[8];
    {
        const f4* hp = (const f4*)&h0[dir*HH + k16*32];
        #pragma unroll
        for (int t = 0; t < 8; t++)
            asm volatile("global_load_dwordx4 %0, %1, off"
                         : "=v"(hvv[t]) : "v"(hp + t));
        asm volatile("s_waitcnt vmcnt(0)" ::: "memory");
        __builtin_amdgcn_sched_barrier(0);
    }

    float xv = 0.f;
    if (k16 < 4) xv = xwD[(size_t)(dir ? TT-1 : 0)*G4 + k16*HH + hidx];

    for (int s = 0; s < TT; s++) {
        // ---- dot over own chunk (registers); 4 gates share hvv ----
        f4 p = {0.f, 0.f, 0.f, 0.f};
        #pragma unroll
        for (int t = 0; t < 8; t++) {
            f4 hv = hvv[t];
            p.x += wreg[0][t].x*hv.x; p.x += wreg[0][t].y*hv.y;
            p.x += wreg[0][t].z*hv.z; p.x += wreg[0][t].w*hv.w;
            p.y += wreg[1][t].x*hv.x; p.y += wreg[1][t].y*hv.y;
            p.y += wreg[1][t].z*hv.z; p.y += wreg[1][t].w*hv.w;
            p.z += wreg[2][t].x*hv.x; p.z += wreg[2][t].y*hv.y;
            p.z += wreg[2][t].z*hv.z; p.z += wreg[2][t].w*hv.w;
            p.w += wreg[3][t].x*hv.x; p.w += wreg[3][t].y*hv.y;
            p.w += wreg[3][t].z*hv.z; p.w += wreg[3][t].w*hv.w;
        }
        // 16-lane butterfly (masks 1,2,4,8 stay inside the hi group)
        #pragma unroll
        for (int m = 1; m < 16; m <<= 1) {
            p.x += __shfl_xor(p.x, m);
            p.y += __shfl_xor(p.y, m);
            p.z += __shfl_xor(p.z, m);
            p.w += __shfl_xor(p.w, m);
        }
        if (k16 < 4) {
            float sv = (k16 == 0) ? p.x : (k16 == 1) ? p.y : (k16 == 2) ? p.z : p.w;
            gv[s & 1][k16*32 + loc] = sv + xv;
        }
        __syncthreads();                                   // A: the ONLY barrier

        const int time = dir ? (TT-1-s) : s;
        if (tid < 32) {
            const int jc = w*32 + tid;
            float gi = gv[s&1][tid],    gf = gv[s&1][32+tid];
            float gg = gv[s&1][64+tid], go = gv[s&1][96+tid];
            float i_ = fsig(gi);
            float f_ = fsig(gf);
            float g_ = ftanh(gg);
            float o_ = fsig(go);
            c = f_*c + i_*g_;
            float hn = o_*ftanh(c);
            if (s+1 < TT) {
                // R1 ordering: 2-step-old canary reset (same slot) complete
                // before this h store. Near-free wait; only these 32 lanes.
                asm volatile("s_waitcnt vmcnt(0)" ::: "memory");
                __hip_atomic_store(&hb[((s+1)&3)*HH + jc], hn,
                                   __ATOMIC_RELAXED, __HIP_MEMORY_SCOPE_AGENT);
                __hip_atomic_store(&hb[((s+3)&3)*HH + jc], CANARY,
                                   __ATOMIC_RELAXED, __HIP_MEMORY_SCOPE_AGENT);
            }
            hcat[(size_t)time*1024 + dir*HH + jc] = hn;    // fire-and-forget
        }

        if (s+1 < TT) {
            if (k16 < 4)
                xv = xwD[(size_t)(dir ? TT-2-s : s+1)*G4 + k16*HH + hidx];

            // direct poll of own 128B chunk into the dot registers
            const f4* base = (const f4*)&hb[((s+1)&3)*HH + k16*32];
            int guard = 0;
            for (;;) {
                #pragma unroll
                for (int t = 0; t < 8; t++)
                    asm volatile("global_load_dwordx4 %0, %1, off sc1"
                                 : "=v"(hvv[t]) : "v"(base + t));
                asm volatile("s_waitcnt vmcnt(0)" ::: "memory");
                __builtin_amdgcn_sched_barrier(0);         // rule #18
                bool ok = true;
                #pragma unroll
                for (int t = 0; t < 8; t++)
                    ok &= (hvv[t].x != CANARY) & (hvv[t].y != CANARY) &
                          (hvv[t].z != CANARY) & (hvv[t].w != CANARY);
                if (ok) break;
                if (++guard > (1<<13)) break;              // fail-visible
            }
        }
    }
}

// ---------------------------------------------------------------------------
// K3: frames[t][j] = dot(hcat[t], Wout[j]) + bout[j]; one block per t.
// (round-3 64-thread version — proven fastest via others-time subtraction)
// ---------------------------------------------------------------------------
__global__ __launch_bounds__(64) void k_frames(
    const float* __restrict__ hcat, const float* __restrict__ Wout,
    const float* __restrict__ bout, float* __restrict__ frames)
{
    const int t = blockIdx.x, tid = threadIdx.x;
    __shared__ float hrow[1024];
    const float4* src  = (const float4*)&hcat[(size_t)t*1024];
    float4* dst4 = (float4*)hrow;
    #pragma unroll
    for (int u = 0; u < 4; u++) dst4[u*64 + tid] = src[u*64 + tid];
    __syncthreads();
    if (tid < NTAGS) {
        float acc = bout[tid];
        const float4* wr = (const float4*)&Wout[(size_t)tid*1024];
        #pragma unroll 16
        for (int e = 0; e < 256; e++) {
            float4 wv = wr[e];
            float4 hv = dst4[e];
            acc += wv.x*hv.x + wv.y*hv.y + wv.z*hv.z + wv.w*hv.w;
        }
        frames[t*NTAGS + tid] = acc;
    }
}

// ---------------------------------------------------------------------------
// K4: Viterbi scan (round-3 version: 2 barriers/step, alpha in LDS)
// + backtrace chased through LDS in 256-row chunks.
// First-max tie-breaking matches jnp.argmax (ascending i, strict >).
// ---------------------------------------------------------------------------
#define CH 256
__global__ __launch_bounds__(256) void k_viterbi(
    const float* __restrict__ frames, const float* __restrict__ trans,
    const int* __restrict__ startp, const int* __restrict__ endp,
    unsigned char* __restrict__ bp, float* __restrict__ out)
{
    const int tid = threadIdx.x;
    const int grp = tid / NTAGS;      // 0..3 compute, 4 = prefetch, rest idle
    const int j   = tid % NTAGS;
    __shared__ float alpha[2][NTAGS];
    __shared__ float red[4][NTAGS];
    __shared__ int   redarg[4][NTAGS];
    __shared__ float frbuf[2][NTAGS];
    __shared__ __align__(16) unsigned char bps[CH*NTAGS];   // 12 KB
    __shared__ int s_tag;

    float tr[12];
    if (grp < 4) {
        #pragma unroll
        for (int u = 0; u < 12; u++) tr[u] = trans[j*NTAGS + grp*12 + u]; // transitions[j][i]
    }
    const int start_tag = *startp;
    if (tid < NTAGS) alpha[0][tid] = (tid == start_tag) ? 0.f : -10000.f;
    const bool is_pf = (tid >= 192 && tid < 192 + NTAGS);
    if (is_pf) frbuf[0][tid-192] = frames[tid-192];
    __syncthreads();

    for (int t = 0; t < TT; t++) {
        float fpre = 0.f;
        if (is_pf && t+1 < TT) fpre = frames[(t+1)*NTAGS + (tid-192)];
        if (grp < 4) {
            float best = -3.0e38f; int barg = 0;
            #pragma unroll
            for (int u = 0; u < 12; u++) {
                float sv = alpha[t&1][grp*12+u] + tr[u];
                if (sv > best) { best = sv; barg = grp*12+u; }
            }
            red[grp][j] = best; redarg[grp][j] = barg;
        }
        __syncthreads();
        if (tid < NTAGS) {
            float b = red[0][tid]; int a = redarg[0][tid];
            #pragma unroll
            for (int g2 = 1; g2 < 4; g2++) {
                float v = red[g2][tid];
                if (v > b) { b = v; a = redarg[g2][tid]; }
            }
            bp[t*NTAGS + tid] = (unsigned char)a;
            alpha[(t+1)&1][tid] = b + frbuf[t&1][tid];
        }
        __syncthreads();
        if (is_pf && t+1 < TT) frbuf[(t+1)&1][tid-192] = fpre;
    }

    if (tid == 0) {
        const int end_tag = *endp;
        float best = -3.0e38f; int bl = 0;
        for (int j2 = 0; j2 < NTAGS; j2++) {
            float v = alpha[0][j2] + trans[end_tag*NTAGS + j2];  // TT even -> parity 0
            if (v > best) { best = v; bl = j2; }
        }
        out[0] = best;
        out[1 + TT - 1] = (float)bl;
        s_tag = bl;
    }
    __syncthreads();

    // chunked backtrace: t = TT-1 .. 1, chunks descending
    for (int base = TT - CH; base >= 0; base -= CH) {
        {   // parallel load of rows [base, base+CH) into LDS (48 B each)
            const float4* srcr = (const float4*)&bp[(size_t)(base + tid)*NTAGS];
            float4* dstr = (float4*)&bps[tid*NTAGS];
            dstr[0] = srcr[0]; dstr[1] = srcr[1]; dstr[2] = srcr[2];
        }
        __syncthreads();
        if (tid == 0) {
            int tag = s_tag;
            const int thi = base + CH - 1;
            const int tlo = (base == 0) ? 1 : base;
            for (int t = thi; t >= tlo; t--) {
                tag = bps[(t - base)*NTAGS + tag];
                out[t] = (float)tag;
            }
            s_tag = tag;
        }
        __syncthreads();
    }
}

extern "C" void kernel_launch(void* const* d_in, const int* in_sizes, int n_in,
                              void* d_out, int out_size, void* d_ws, size_t ws_size,
                              hipStream_t stream)
{
    const int*   words = (const int*)  d_in[0];
    const float* embed = (const float*)d_in[1];
    const float* WihF  = (const float*)d_in[2];
    const float* WhhF  = (const float*)d_in[3];
    const float* bihF  = (const float*)d_in[4];
    const float* bhhF  = (const float*)d_in[5];
    const float* WihB  = (const float*)d_in[6];
    const float* WhhB  = (const float*)d_in[7];
    const float* bihB  = (const float*)d_in[8];
    const float* bhhB  = (const float*)d_in[9];
    const float* Wout  = (const float*)d_in[10];
    const float* bout  = (const float*)d_in[11];
    const float* trans = (const float*)d_in[12];
    const float* h0    = (const float*)d_in[13];
    const float* c0    = (const float*)d_in[14];
    const int*   startp= (const int*)  d_in[15];
    const int*   endp  = (const int*)  d_in[16];

    char* ws = (char*)d_ws;
    float* xw   = (float*)(ws + OFF_XW);
    float* hcat = (float*)(ws + OFF_HCAT);
    float* frm  = (float*)(ws + OFF_FRM);
    float* hbuf = (float*)(ws + OFF_HBUF);
    unsigned char* bp = (unsigned char*)(ws + OFF_BP);

    dim3 g1(32, 32, 2);
    k_xw<<<g1, 256, 0, stream>>>(words, embed, WihF, WihB, bihF, bhhF,
                                 bihB, bhhB, xw, hbuf);
    k_lstm<<<dim3(2*NWG), 512, 0, stream>>>(WhhF, WhhB, h0, c0, xw, hbuf, hcat);
    k_frames<<<dim3(TT), 64, 0, stream>>>(hcat, Wout, bout, frm);
    k_viterbi<<<dim3(1), 256, 0, stream>>>(frm, trans, startp, endp, bp, (float*)d_out);
}

// Round 16
// 5448.697 us; speedup vs baseline: 1.7004x; 1.7004x over previous
//
#include <hip/hip_runtime.h>

#define TT 2048
#define HH 512
#define EE 512
#define NTAGS 48
#define G4 2048   // 4*HH
#define NWG 16    // workgroups per direction in the LSTM kernel
#define CANARY 1.0e30f

typedef float f4 __attribute__((ext_vector_type(4)));

// workspace byte offsets
#define OFF_XW    0ULL                                      // [2][TT][G4] f32 = 32 MB
#define OFF_HCAT  (OFF_XW   + 2ULL*TT*G4*4ULL)              // [TT][1024] f32 = 8 MB
#define OFF_FRM   (OFF_HCAT + (unsigned long long)TT*1024ULL*4ULL) // [TT][48] f32
#define OFF_HBUF  (OFF_FRM  + (unsigned long long)TT*NTAGS*4ULL)   // [2][4][HH] f32 (canary slots)
#define OFF_BP    (OFF_HBUF + 2ULL*4ULL*HH*4ULL)            // [TT][48] u8

// fast activations: v_exp_f32 + v_rcp_f32 (rel err ~1e-6; output threshold 106)
__device__ __forceinline__ float fsig(float x) {
    return __builtin_amdgcn_rcpf(1.f + __expf(-x));
}
__device__ __forceinline__ float ftanh(float x) {
    return 1.f - 2.f*__builtin_amdgcn_rcpf(__expf(2.f*x) + 1.f);
}

// ---------------------------------------------------------------------------
// K1: xW[dir][t][r] = sum_e embed[words[t]][e]*Wih[dir][r][e] + bih[r]+bhh[r]
// 64x64 tile, 256 threads, 4x4 micro-tile, K-chunk 32. Also canary-fills the
// LSTM h exchange slots. (unchanged)
// ---------------------------------------------------------------------------
__global__ __launch_bounds__(256) void k_xw(
    const int* __restrict__ words, const float* __restrict__ embed,
    const float* __restrict__ WihF, const float* __restrict__ WihB,
    const float* __restrict__ bihF, const float* __restrict__ bhhF,
    const float* __restrict__ bihB, const float* __restrict__ bhhB,
    float* __restrict__ xw, float* __restrict__ hbuf)
{
    const int tid = threadIdx.x;
    const int bx = blockIdx.x, by = blockIdx.y, dir = blockIdx.z;

    if (bx == 0 && by == 0) {                   // one block per dir: canary fill
        for (int j = tid; j < 4*HH; j += 256)
            hbuf[dir*4*HH + j] = CANARY;
    }

    const float* Wih = dir ? WihB : WihF;
    const float* bi  = dir ? bihB : bihF;
    const float* bh  = dir ? bhhB : bhhF;

    __shared__ float sa[32][64];
    __shared__ float sb[32][64];
    __shared__ int   wds[64];
    if (tid < 64) wds[tid] = words[by*64 + tid];
    const int tx = tid & 15, ty = tid >> 4;
    float acc[4][4] = {};
    __syncthreads();

    for (int k0 = 0; k0 < EE; k0 += 32) {
        #pragma unroll
        for (int u = 0; u < 2; u++) {
            int idx = tid*2 + u;            // 0..511
            int row = idx >> 3, kq = idx & 7;
            float4 av = *(const float4*)&embed[(size_t)wds[row]*EE + k0 + kq*4];
            float4 bv = *(const float4*)&Wih[(size_t)(bx*64 + row)*EE + k0 + kq*4];
            sa[kq*4+0][row] = av.x; sa[kq*4+1][row] = av.y;
            sa[kq*4+2][row] = av.z; sa[kq*4+3][row] = av.w;
            sb[kq*4+0][row] = bv.x; sb[kq*4+1][row] = bv.y;
            sb[kq*4+2][row] = bv.z; sb[kq*4+3][row] = bv.w;
        }
        __syncthreads();
        #pragma unroll
        for (int k = 0; k < 32; k++) {
            float4 a = *(const float4*)&sa[k][ty*4];
            float4 b = *(const float4*)&sb[k][tx*4];
            acc[0][0] += a.x*b.x; acc[0][1] += a.x*b.y; acc[0][2] += a.x*b.z; acc[0][3] += a.x*b.w;
            acc[1][0] += a.y*b.x; acc[1][1] += a.y*b.y; acc[1][2] += a.y*b.z; acc[1][3] += a.y*b.w;
            acc[2][0] += a.z*b.x; acc[2][1] += a.z*b.y; acc[2][2] += a.z*b.z; acc[2][3] += a.z*b.w;
            acc[3][0] += a.w*b.x; acc[3][1] += a.w*b.y; acc[3][2] += a.w*b.z; acc[3][3] += a.w*b.w;
        }
        __syncthreads();
    }

    float* outp = xw + (size_t)dir*TT*G4;
    const int rbase = bx*64 + tx*4;
    float4 bi4 = *(const float4*)&bi[rbase];
    float4 bh4 = *(const float4*)&bh[rbase];
    float4 bias = make_float4(bi4.x+bh4.x, bi4.y+bh4.y, bi4.z+bh4.z, bi4.w+bh4.w);
    #pragma unroll
    for (int i = 0; i < 4; i++) {
        int t = by*64 + ty*4 + i;
        float4 v = make_float4(acc[i][0]+bias.x, acc[i][1]+bias.y,
                               acc[i][2]+bias.z, acc[i][3]+bias.w);
        *(float4*)&outp[(size_t)t*G4 + rbase] = v;
    }
}

// ---------------------------------------------------------------------------
// K2: Bi-LSTM recurrence — ROUND-13 VERBATIM (best measured: 3727us).
// R3 structure; asm-opaque weights; HW activations; producer-only vmcnt(0);
// 2-deep pipelined poll with rule-#18 sched_barrier fences; 4-slot canary
// LLC exchange; 2 barriers/step. Six perturbations of this (backoff, scope,
// width, poll pipelining alone, LDS layout, direct-register poll) were null
// or regressions — this is the measured optimum of the topology.
// ---------------------------------------------------------------------------
__global__ __launch_bounds__(512, 2) void k_lstm(
    const float* __restrict__ WhhF, const float* __restrict__ WhhB,
    const float* __restrict__ h0, const float* __restrict__ c0,
    const float* __restrict__ xw,
    float* __restrict__ hbuf, float* __restrict__ hcat)
{
    const int bid = blockIdx.x;
    const int dir = bid >> 4;
    const int w   = bid & 15;
    const float* Whh = dir ? WhhB : WhhF;
    const float* xwD = xw + (size_t)dir*TT*G4;
    float* hb = hbuf + dir*4*HH;        // [slot][HH]

    const int tid  = threadIdx.x;
    const int rl   = tid >> 2;          // 0..127 local row
    const int q    = tid & 3;           // quarter of the K=512 dot
    const int gate = rl >> 5;           // 0:i 1:f 2:g 3:o
    const int jj   = rl & 31;
    const int row  = gate*HH + w*32 + jj;   // global row in [0,2048)

    // Whh quarter-row via asm loads (opaque to rematerialization)
    f4 wreg[32];
    {
        const f4* wr = (const f4*)&Whh[(size_t)row*HH + q*128];
        #pragma unroll
        for (int k = 0; k < 32; k++)
            asm volatile("global_load_dwordx4 %0, %1, off"
                         : "=v"(wreg[k]) : "v"(wr + k));
        asm volatile("s_waitcnt vmcnt(0)" ::: "memory");
        __builtin_amdgcn_sched_barrier(0);      // rule #18: pin reads after wait
    }
    float c = 0.f;
    if (tid < 32) c = c0[dir*HH + w*32 + tid];

    __shared__ __align__(16) float hsh[2064];   // 4 replicas, stride 516 (bank-skewed)
    __shared__ float gv[128];

    {   // initial h (parity 0)
        float hv = h0[dir*HH + tid];
        #pragma unroll
        for (int r = 0; r < 4; r++) hsh[r*516 + tid] = hv;
    }
    __syncthreads();

    const float* hq = &hsh[q*644];      // replica q, offset q*128 folded (516q+128q)

    float xv = 0.f;
    if (q == 0) xv = xwD[(size_t)(dir ? TT-1 : 0)*G4 + row];

    for (int s = 0; s < TT; s++) {
        float p0=0.f,p1=0.f,p2=0.f,p3=0.f;
        #pragma unroll
        for (int k = 0; k < 32; k++) {
            float4 hv = *(const float4*)&hq[4*k];
            p0 += wreg[k].x*hv.x; p1 += wreg[k].y*hv.y;
            p2 += wreg[k].z*hv.z; p3 += wreg[k].w*hv.w;
        }
        float part = (p0+p1)+(p2+p3);
        part += __shfl_xor(part, 1);
        part += __shfl_xor(part, 2);
        if (q == 0) gv[rl] = part + xv;
        __syncthreads();                                   // A: gv ready

        const int time = dir ? (TT-1-s) : s;
        if (tid < 32) {
            const int jc = w*32 + tid;
            float gi = gv[tid], gf = gv[32+tid], gg = gv[64+tid], go = gv[96+tid];
            float i_ = fsig(gi);
            float f_ = fsig(gf);
            float g_ = ftanh(gg);
            float o_ = fsig(go);
            c = f_*c + i_*g_;
            float hn = o_*ftanh(c);
            if (s+1 < TT) {
                // R1 ordering: this lane's 2-step-old canary reset (same
                // slot as the h store) must be complete. Near-free wait.
                asm volatile("s_waitcnt vmcnt(0)" ::: "memory");
                __hip_atomic_store(&hb[((s+1)&3)*HH + jc], hn,
                                   __ATOMIC_RELAXED, __HIP_MEMORY_SCOPE_AGENT);
                __hip_atomic_store(&hb[((s+3)&3)*HH + jc], CANARY,
                                   __ATOMIC_RELAXED, __HIP_MEMORY_SCOPE_AGENT);
            }
            hcat[(size_t)time*1024 + dir*HH + jc] = hn;    // fire-and-forget
        }

        if (s+1 < TT) {
            float xv_next = 0.f;
            if (q == 0) xv_next = xwD[(size_t)(dir ? TT-2-s : s+1)*G4 + row];

            // 2-deep pipelined poll of own element, rule-#18 fenced
            const float* addr = &hb[((s+1)&3)*HH + tid];
            float va, vb = CANARY; int guard = 0;
            asm volatile("global_load_dword %0, %1, off sc1"
                         : "=v"(va) : "v"(addr));
            for (;;) {
                asm volatile("global_load_dword %0, %1, off sc1"
                             : "=v"(vb) : "v"(addr));
                asm volatile("s_waitcnt vmcnt(1)" ::: "memory");   // va ready
                __builtin_amdgcn_sched_barrier(0);
                if (va != CANARY) break;
                asm volatile("global_load_dword %0, %1, off sc1"
                             : "=v"(va) : "v"(addr));
                asm volatile("s_waitcnt vmcnt(1)" ::: "memory");   // vb ready
                __builtin_amdgcn_sched_barrier(0);
                if (vb != CANARY) break;
                if (++guard > (1<<14)) break;              // fail-visible
            }
            asm volatile("s_waitcnt vmcnt(0)" ::: "memory");       // drain
            __builtin_amdgcn_sched_barrier(0);
            float hv = (va != CANARY) ? va : vb;   // slot is canary->h monotone
            #pragma unroll
            for (int r = 0; r < 4; r++) hsh[r*516 + tid] = hv;
            xv = xv_next;
            __syncthreads();                               // D: restage done
        }
    }
}

// ---------------------------------------------------------------------------
// K3: frames[t][j] = dot(hcat[t], Wout[j]) + bout[j]; one block per t.
// (round-3 64-thread version — proven fastest via others-time subtraction)
// ---------------------------------------------------------------------------
__global__ __launch_bounds__(64) void k_frames(
    const float* __restrict__ hcat, const float* __restrict__ Wout,
    const float* __restrict__ bout, float* __restrict__ frames)
{
    const int t = blockIdx.x, tid = threadIdx.x;
    __shared__ float hrow[1024];
    const float4* src  = (const float4*)&hcat[(size_t)t*1024];
    float4* dst4 = (float4*)hrow;
    #pragma unroll
    for (int u = 0; u < 4; u++) dst4[u*64 + tid] = src[u*64 + tid];
    __syncthreads();
    if (tid < NTAGS) {
        float acc = bout[tid];
        const float4* wr = (const float4*)&Wout[(size_t)tid*1024];
        #pragma unroll 16
        for (int e = 0; e < 256; e++) {
            float4 wv = wr[e];
            float4 hv = dst4[e];
            acc += wv.x*hv.x + wv.y*hv.y + wv.z*hv.z + wv.w*hv.w;
        }
        frames[t*NTAGS + tid] = acc;
    }
}

// ---------------------------------------------------------------------------
// K4: Viterbi scan, SINGLE WAVE (64 lanes), ZERO barriers in the main loop.
// Lane j holds alpha[j] and trans[j][0..47] in registers. Per step the
// 48-wide max runs as 4 independent 12-deep chains over shfl-broadcast
// alpha[i] (ascending index within chains + ascending merge = jnp.argmax
// first-max semantics). bp row stored fire-and-forget; frames prefetched
// one step ahead. Backtrace: chunked LDS chase, 4 rows/thread loads.
// ---------------------------------------------------------------------------
#define CH 256
__global__ __launch_bounds__(64) void k_viterbi(
    const float* __restrict__ frames, const float* __restrict__ trans,
    const int* __restrict__ startp, const int* __restrict__ endp,
    unsigned char* __restrict__ bp, float* __restrict__ out)
{
    const int j = threadIdx.x;        // 0..63; lanes 48-63 idle-ish
    __shared__ float afinal[NTAGS];
    __shared__ __align__(16) unsigned char bps[CH*NTAGS];   // 12 KB
    __shared__ int s_tag;

    float tr[NTAGS];
    float alpha = -3.0e38f;
    const int start_tag = *startp;
    if (j < NTAGS) {
        #pragma unroll
        for (int i = 0; i < NTAGS; i++) tr[i] = trans[j*NTAGS + i]; // transitions[j][i]
        alpha = (j == start_tag) ? 0.f : -10000.f;
    }
    float fcur = (j < NTAGS) ? frames[j] : 0.f;

    for (int t = 0; t < TT; t++) {
        float fnext = 0.f;
        if (j < NTAGS && t+1 < TT) fnext = frames[(t+1)*NTAGS + j];  // prefetch

        // 4 independent 12-deep argmax chains (ILP), ascending index
        float b0 = -3.0e38f, b1 = -3.0e38f, b2 = -3.0e38f, b3 = -3.0e38f;
        int   a0 = 0, a1 = 12, a2 = 24, a3 = 36;
        #pragma unroll
        for (int u = 0; u < 12; u++) {
            float s0 = __shfl(alpha, u)      + tr[u];
            float s1 = __shfl(alpha, 12 + u) + tr[12 + u];
            float s2 = __shfl(alpha, 24 + u) + tr[24 + u];
            float s3 = __shfl(alpha, 36 + u) + tr[36 + u];
            if (s0 > b0) { b0 = s0; a0 = u; }
            if (s1 > b1) { b1 = s1; a1 = 12 + u; }
            if (s2 > b2) { b2 = s2; a2 = 24 + u; }
            if (s3 > b3) { b3 = s3; a3 = 36 + u; }
        }
        float best = b0; int barg = a0;            // ascending merge: first-max
        if (b1 > best) { best = b1; barg = a1; }
        if (b2 > best) { best = b2; barg = a2; }
        if (b3 > best) { best = b3; barg = a3; }

        if (j < NTAGS) {
            bp[t*NTAGS + j] = (unsigned char)barg;   // fire-and-forget
            alpha = best + fcur;
        }
        fcur = fnext;
    }
    if (j < NTAGS) afinal[j] = alpha;
    __syncthreads();                  // single wave: compiles to waitcnt only

    if (j == 0) {
        const int end_tag = *endp;
        float best = -3.0e38f; int bl = 0;
        for (int j2 = 0; j2 < NTAGS; j2++) {
            float v = afinal[j2] + trans[end_tag*NTAGS + j2];
            if (v > best) { best = v; bl = j2; }
        }
        out[0] = best;
        out[1 + TT - 1] = (float)bl;
        s_tag = bl;
    }
    __syncthreads();

    // chunked backtrace: t = TT-1 .. 1, chunks descending; 4 rows per thread
    for (int base = TT - CH; base >= 0; base -= CH) {
        #pragma unroll
        for (int u = 0; u < 4; u++) {
            const int row = u*64 + j;             // 0..255
            const float4* srcr = (const float4*)&bp[(size_t)(base + row)*NTAGS];
            float4* dstr = (float4*)&bps[row*NTAGS];
            dstr[0] = srcr[0]; dstr[1] = srcr[1]; dstr[2] = srcr[2];
        }
        __syncthreads();
        if (j == 0) {
            int tag = s_tag;
            const int thi = base + CH - 1;
            const int tlo = (base == 0) ? 1 : base;
            for (int t = thi; t >= tlo; t--) {
                tag = bps[(t - base)*NTAGS + tag];
                out[t] = (float)tag;
            }
            s_tag = tag;
        }
        __syncthreads();
    }
}

extern "C" void kernel_launch(void* const* d_in, const int* in_sizes, int n_in,
                              void* d_out, int out_size, void* d_ws, size_t ws_size,
                              hipStream_t stream)
{
    const int*   words = (const int*)  d_in[0];
    const float* embed = (const float*)d_in[1];
    const float* WihF  = (const float*)d_in[2];
    const float* WhhF  = (const float*)d_in[3];
    const float* bihF  = (const float*)d_in[4];
    const float* bhhF  = (const float*)d_in[5];
    const float* WihB  = (const float*)d_in[6];
    const float* WhhB  = (const float*)d_in[7];
    const float* bihB  = (const float*)d_in[8];
    const float* bhhB  = (const float*)d_in[9];
    const float* Wout  = (const float*)d_in[10];
    const float* bout  = (const float*)d_in[11];
    const float* trans = (const float*)d_in[12];
    const float* h0    = (const float*)d_in[13];
    const float* c0    = (const float*)d_in[14];
    const int*   startp= (const int*)  d_in[15];
    const int*   endp  = (const int*)  d_in[16];

    char* ws = (char*)d_ws;
    float* xw   = (float*)(ws + OFF_XW);
    float* hcat = (float*)(ws + OFF_HCAT);
    float* frm  = (float*)(ws + OFF_FRM);
    float* hbuf = (float*)(ws + OFF_HBUF);
    unsigned char* bp = (unsigned char*)(ws + OFF_BP);

    dim3 g1(32, 32, 2);
    k_xw<<<g1, 256, 0, stream>>>(words, embed, WihF, WihB, bihF, bhhF,
                                 bihB, bhhB, xw, hbuf);
    k_lstm<<<dim3(2*NWG), 512, 0, stream>>>(WhhF, WhhB, h0, c0, xw, hbuf, hcat);
    k_frames<<<dim3(TT), 64, 0, stream>>>(hcat, Wout, bout, frm);
    k_viterbi<<<dim3(1), 64, 0, stream>>>(frm, trans, startp, endp, bp, (float*)d_out);
}

// Round 17
// 4809.326 us; speedup vs baseline: 1.9265x; 1.1329x over previous
//
#include <hip/hip_runtime.h>

#define TT 2048
#define HH 512
#define EE 512
#define NTAGS 48
#define G4 2048   // 4*HH
#define NWG 16    // workgroups per direction in the LSTM kernel
#define CANARY 1.0e30f

typedef float f4 __attribute__((ext_vector_type(4)));

// workspace byte offsets
#define OFF_XW    0ULL                                      // [2][TT][G4] f32 = 32 MB
#define OFF_HCAT  (OFF_XW   + 2ULL*TT*G4*4ULL)              // [TT][1024] f32 = 8 MB
#define OFF_FRM   (OFF_HCAT + (unsigned long long)TT*1024ULL*4ULL) // [TT][48] f32
#define OFF_HBUF  (OFF_FRM  + (unsigned long long)TT*NTAGS*4ULL)   // [2][4][HH] f32 (canary slots)
#define OFF_BP    (OFF_HBUF + 2ULL*4ULL*HH*4ULL)            // [TT][48] u8

// fast activations: v_exp_f32 + v_rcp_f32 (rel err ~1e-6; output threshold 106)
__device__ __forceinline__ float fsig(float x) {
    return __builtin_amdgcn_rcpf(1.f + __expf(-x));
}
__device__ __forceinline__ float ftanh(float x) {
    return 1.f - 2.f*__builtin_amdgcn_rcpf(__expf(2.f*x) + 1.f);
}

// ---------------------------------------------------------------------------
// K1: xW[dir][t][r] = sum_e embed[words[t]][e]*Wih[dir][r][e] + bih[r]+bhh[r]
// 64x64 tile, 256 threads, 4x4 micro-tile, K-chunk 32. Also canary-fills the
// LSTM h exchange slots.
// ---------------------------------------------------------------------------
__global__ __launch_bounds__(256) void k_xw(
    const int* __restrict__ words, const float* __restrict__ embed,
    const float* __restrict__ WihF, const float* __restrict__ WihB,
    const float* __restrict__ bihF, const float* __restrict__ bhhF,
    const float* __restrict__ bihB, const float* __restrict__ bhhB,
    float* __restrict__ xw, float* __restrict__ hbuf)
{
    const int tid = threadIdx.x;
    const int bx = blockIdx.x, by = blockIdx.y, dir = blockIdx.z;

    if (bx == 0 && by == 0) {                   // one block per dir: canary fill
        for (int j = tid; j < 4*HH; j += 256)
            hbuf[dir*4*HH + j] = CANARY;
    }

    const float* Wih = dir ? WihB : WihF;
    const float* bi  = dir ? bihB : bihF;
    const float* bh  = dir ? bhhB : bhhF;

    __shared__ float sa[32][64];
    __shared__ float sb[32][64];
    __shared__ int   wds[64];
    if (tid < 64) wds[tid] = words[by*64 + tid];
    const int tx = tid & 15, ty = tid >> 4;
    float acc[4][4] = {};
    __syncthreads();

    for (int k0 = 0; k0 < EE; k0 += 32) {
        #pragma unroll
        for (int u = 0; u < 2; u++) {
            int idx = tid*2 + u;            // 0..511
            int row = idx >> 3, kq = idx & 7;
            float4 av = *(const float4*)&embed[(size_t)wds[row]*EE + k0 + kq*4];
            float4 bv = *(const float4*)&Wih[(size_t)(bx*64 + row)*EE + k0 + kq*4];
            sa[kq*4+0][row] = av.x; sa[kq*4+1][row] = av.y;
            sa[kq*4+2][row] = av.z; sa[kq*4+3][row] = av.w;
            sb[kq*4+0][row] = bv.x; sb[kq*4+1][row] = bv.y;
            sb[kq*4+2][row] = bv.z; sb[kq*4+3][row] = bv.w;
        }
        __syncthreads();
        #pragma unroll
        for (int k = 0; k < 32; k++) {
            float4 a = *(const float4*)&sa[k][ty*4];
            float4 b = *(const float4*)&sb[k][tx*4];
            acc[0][0] += a.x*b.x; acc[0][1] += a.x*b.y; acc[0][2] += a.x*b.z; acc[0][3] += a.x*b.w;
            acc[1][0] += a.y*b.x; acc[1][1] += a.y*b.y; acc[1][2] += a.y*b.z; acc[1][3] += a.y*b.w;
            acc[2][0] += a.z*b.x; acc[2][1] += a.z*b.y; acc[2][2] += a.z*b.z; acc[2][3] += a.z*b.w;
            acc[3][0] += a.w*b.x; acc[3][1] += a.w*b.y; acc[3][2] += a.w*b.z; acc[3][3] += a.w*b.w;
        }
        __syncthreads();
    }

    float* outp = xw + (size_t)dir*TT*G4;
    const int rbase = bx*64 + tx*4;
    float4 bi4 = *(const float4*)&bi[rbase];
    float4 bh4 = *(const float4*)&bh[rbase];
    float4 bias = make_float4(bi4.x+bh4.x, bi4.y+bh4.y, bi4.z+bh4.z, bi4.w+bh4.w);
    #pragma unroll
    for (int i = 0; i < 4; i++) {
        int t = by*64 + ty*4 + i;
        float4 v = make_float4(acc[i][0]+bias.x, acc[i][1]+bias.y,
                               acc[i][2]+bias.z, acc[i][3]+bias.w);
        *(float4*)&outp[(size_t)t*G4 + rbase] = v;
    }
}

// ---------------------------------------------------------------------------
// K2: Bi-LSTM recurrence — ROUND-13 VERBATIM (best measured: 3727us).
// R3 structure; asm-opaque weights; HW activations; producer-only vmcnt(0);
// 2-deep pipelined poll with rule-#18 sched_barrier fences; 4-slot canary
// LLC exchange; 2 barriers/step.
// ---------------------------------------------------------------------------
__global__ __launch_bounds__(512, 2) void k_lstm(
    const float* __restrict__ WhhF, const float* __restrict__ WhhB,
    const float* __restrict__ h0, const float* __restrict__ c0,
    const float* __restrict__ xw,
    float* __restrict__ hbuf, float* __restrict__ hcat)
{
    const int bid = blockIdx.x;
    const int dir = bid >> 4;
    const int w   = bid & 15;
    const float* Whh = dir ? WhhB : WhhF;
    const float* xwD = xw + (size_t)dir*TT*G4;
    float* hb = hbuf + dir*4*HH;        // [slot][HH]

    const int tid  = threadIdx.x;
    const int rl   = tid >> 2;          // 0..127 local row
    const int q    = tid & 3;           // quarter of the K=512 dot
    const int gate = rl >> 5;           // 0:i 1:f 2:g 3:o
    const int jj   = rl & 31;
    const int row  = gate*HH + w*32 + jj;   // global row in [0,2048)

    // Whh quarter-row via asm loads (opaque to rematerialization)
    f4 wreg[32];
    {
        const f4* wr = (const f4*)&Whh[(size_t)row*HH + q*128];
        #pragma unroll
        for (int k = 0; k < 32; k++)
            asm volatile("global_load_dwordx4 %0, %1, off"
                         : "=v"(wreg[k]) : "v"(wr + k));
        asm volatile("s_waitcnt vmcnt(0)" ::: "memory");
        __builtin_amdgcn_sched_barrier(0);      // rule #18: pin reads after wait
    }
    float c = 0.f;
    if (tid < 32) c = c0[dir*HH + w*32 + tid];

    __shared__ __align__(16) float hsh[2064];   // 4 replicas, stride 516 (bank-skewed)
    __shared__ float gv[128];

    {   // initial h (parity 0)
        float hv = h0[dir*HH + tid];
        #pragma unroll
        for (int r = 0; r < 4; r++) hsh[r*516 + tid] = hv;
    }
    __syncthreads();

    const float* hq = &hsh[q*644];      // replica q, offset q*128 folded (516q+128q)

    float xv = 0.f;
    if (q == 0) xv = xwD[(size_t)(dir ? TT-1 : 0)*G4 + row];

    for (int s = 0; s < TT; s++) {
        float p0=0.f,p1=0.f,p2=0.f,p3=0.f;
        #pragma unroll
        for (int k = 0; k < 32; k++) {
            float4 hv = *(const float4*)&hq[4*k];
            p0 += wreg[k].x*hv.x; p1 += wreg[k].y*hv.y;
            p2 += wreg[k].z*hv.z; p3 += wreg[k].w*hv.w;
        }
        float part = (p0+p1)+(p2+p3);
        part += __shfl_xor(part, 1);
        part += __shfl_xor(part, 2);
        if (q == 0) gv[rl] = part + xv;
        __syncthreads();                                   // A: gv ready

        const int time = dir ? (TT-1-s) : s;
        if (tid < 32) {
            const int jc = w*32 + tid;
            float gi = gv[tid], gf = gv[32+tid], gg = gv[64+tid], go = gv[96+tid];
            float i_ = fsig(gi);
            float f_ = fsig(gf);
            float g_ = ftanh(gg);
            float o_ = fsig(go);
            c = f_*c + i_*g_;
            float hn = o_*ftanh(c);
            if (s+1 < TT) {
                // R1 ordering: this lane's 2-step-old canary reset (same
                // slot as the h store) must be complete. Near-free wait.
                asm volatile("s_waitcnt vmcnt(0)" ::: "memory");
                __hip_atomic_store(&hb[((s+1)&3)*HH + jc], hn,
                                   __ATOMIC_RELAXED, __HIP_MEMORY_SCOPE_AGENT);
                __hip_atomic_store(&hb[((s+3)&3)*HH + jc], CANARY,
                                   __ATOMIC_RELAXED, __HIP_MEMORY_SCOPE_AGENT);
            }
            hcat[(size_t)time*1024 + dir*HH + jc] = hn;    // fire-and-forget
        }

        if (s+1 < TT) {
            float xv_next = 0.f;
            if (q == 0) xv_next = xwD[(size_t)(dir ? TT-2-s : s+1)*G4 + row];

            // 2-deep pipelined poll of own element, rule-#18 fenced
            const float* addr = &hb[((s+1)&3)*HH + tid];
            float va, vb = CANARY; int guard = 0;
            asm volatile("global_load_dword %0, %1, off sc1"
                         : "=v"(va) : "v"(addr));
            for (;;) {
                asm volatile("global_load_dword %0, %1, off sc1"
                             : "=v"(vb) : "v"(addr));
                asm volatile("s_waitcnt vmcnt(1)" ::: "memory");   // va ready
                __builtin_amdgcn_sched_barrier(0);
                if (va != CANARY) break;
                asm volatile("global_load_dword %0, %1, off sc1"
                             : "=v"(va) : "v"(addr));
                asm volatile("s_waitcnt vmcnt(1)" ::: "memory");   // vb ready
                __builtin_amdgcn_sched_barrier(0);
                if (vb != CANARY) break;
                if (++guard > (1<<14)) break;              // fail-visible
            }
            asm volatile("s_waitcnt vmcnt(0)" ::: "memory");       // drain
            __builtin_amdgcn_sched_barrier(0);
            float hv = (va != CANARY) ? va : vb;   // slot is canary->h monotone
            #pragma unroll
            for (int r = 0; r < 4; r++) hsh[r*516 + tid] = hv;
            xv = xv_next;
            __syncthreads();                               // D: restage done
        }
    }
}

// ---------------------------------------------------------------------------
// K3: frames[t][j] = dot(hcat[t], Wout[j]) + bout[j]; one block per t.
// (round-3 64-thread version — proven fastest via others-time subtraction)
// ---------------------------------------------------------------------------
__global__ __launch_bounds__(64) void k_frames(
    const float* __restrict__ hcat, const float* __restrict__ Wout,
    const float* __restrict__ bout, float* __restrict__ frames)
{
    const int t = blockIdx.x, tid = threadIdx.x;
    __shared__ float hrow[1024];
    const float4* src  = (const float4*)&hcat[(size_t)t*1024];
    float4* dst4 = (float4*)hrow;
    #pragma unroll
    for (int u = 0; u < 4; u++) dst4[u*64 + tid] = src[u*64 + tid];
    __syncthreads();
    if (tid < NTAGS) {
        float acc = bout[tid];
        const float4* wr = (const float4*)&Wout[(size_t)tid*1024];
        #pragma unroll 16
        for (int e = 0; e < 256; e++) {
            float4 wv = wr[e];
            float4 hv = dst4[e];
            acc += wv.x*hv.x + wv.y*hv.y + wv.z*hv.z + wv.w*hv.w;
        }
        frames[t*NTAGS + tid] = acc;
    }
}

// ---------------------------------------------------------------------------
// K4: Viterbi scan (round-3 version: 2 barriers/step, alpha in LDS — proven
// optimum of 3 variants tried) + backtrace chased through LDS in 256-row
// chunks. First-max tie-breaking matches jnp.argmax (ascending i, strict >).
// ---------------------------------------------------------------------------
#define CH 256
__global__ __launch_bounds__(256) void k_viterbi(
    const float* __restrict__ frames, const float* __restrict__ trans,
    const int* __restrict__ startp, const int* __restrict__ endp,
    unsigned char* __restrict__ bp, float* __restrict__ out)
{
    const int tid = threadIdx.x;
    const int grp = tid / NTAGS;      // 0..3 compute, 4 = prefetch, rest idle
    const int j   = tid % NTAGS;
    __shared__ float alpha[2][NTAGS];
    __shared__ float red[4][NTAGS];
    __shared__ int   redarg[4][NTAGS];
    __shared__ float frbuf[2][NTAGS];
    __shared__ __align__(16) unsigned char bps[CH*NTAGS];   // 12 KB
    __shared__ int s_tag;

    float tr[12];
    if (grp < 4) {
        #pragma unroll
        for (int u = 0; u < 12; u++) tr[u] = trans[j*NTAGS + grp*12 + u]; // transitions[j][i]
    }
    const int start_tag = *startp;
    if (tid < NTAGS) alpha[0][tid] = (tid == start_tag) ? 0.f : -10000.f;
    const bool is_pf = (tid >= 192 && tid < 192 + NTAGS);
    if (is_pf) frbuf[0][tid-192] = frames[tid-192];
    __syncthreads();

    for (int t = 0; t < TT; t++) {
        float fpre = 0.f;
        if (is_pf && t+1 < TT) fpre = frames[(t+1)*NTAGS + (tid-192)];
        if (grp < 4) {
            float best = -3.0e38f; int barg = 0;
            #pragma unroll
            for (int u = 0; u < 12; u++) {
                float sv = alpha[t&1][grp*12+u] + tr[u];
                if (sv > best) { best = sv; barg = grp*12+u; }
            }
            red[grp][j] = best; redarg[grp][j] = barg;
        }
        __syncthreads();
        if (tid < NTAGS) {
            float b = red[0][tid]; int a = redarg[0][tid];
            #pragma unroll
            for (int g2 = 1; g2 < 4; g2++) {
                float v = red[g2][tid];
                if (v > b) { b = v; a = redarg[g2][tid]; }
            }
            bp[t*NTAGS + tid] = (unsigned char)a;
            alpha[(t+1)&1][tid] = b + frbuf[t&1][tid];
        }
        __syncthreads();
        if (is_pf && t+1 < TT) frbuf[(t+1)&1][tid-192] = fpre;
    }

    if (tid == 0) {
        const int end_tag = *endp;
        float best = -3.0e38f; int bl = 0;
        for (int j2 = 0; j2 < NTAGS; j2++) {
            float v = alpha[0][j2] + trans[end_tag*NTAGS + j2];  // TT even -> parity 0
            if (v > best) { best = v; bl = j2; }
        }
        out[0] = best;
        out[1 + TT - 1] = (float)bl;
        s_tag = bl;
    }
    __syncthreads();

    // chunked backtrace: t = TT-1 .. 1, chunks descending
    for (int base = TT - CH; base >= 0; base -= CH) {
        {   // parallel load of rows [base, base+CH) into LDS (48 B each)
            const float4* srcr = (const float4*)&bp[(size_t)(base + tid)*NTAGS];
            float4* dstr = (float4*)&bps[tid*NTAGS];
            dstr[0] = srcr[0]; dstr[1] = srcr[1]; dstr[2] = srcr[2];
        }
        __syncthreads();
        if (tid == 0) {
            int tag = s_tag;
            const int thi = base + CH - 1;
            const int tlo = (base == 0) ? 1 : base;
            for (int t = thi; t >= tlo; t--) {
                tag = bps[(t - base)*NTAGS + tag];
                out[t] = (float)tag;
            }
            s_tag = tag;
        }
        __syncthreads();
    }
}

extern "C" void kernel_launch(void* const* d_in, const int* in_sizes, int n_in,
                              void* d_out, int out_size, void* d_ws, size_t ws_size,
                              hipStream_t stream)
{
    const int*   words = (const int*)  d_in[0];
    const float* embed = (const float*)d_in[1];
    const float* WihF  = (const float*)d_in[2];
    const float* WhhF  = (const float*)d_in[3];
    const float* bihF  = (const float*)d_in[4];
    const float* bhhF  = (const float*)d_in[5];
    const float* WihB  = (const float*)d_in[6];
    const float* WhhB  = (const float*)d_in[7];
    const float* bihB  = (const float*)d_in[8];
    const float* bhhB  = (const float*)d_in[9];
    const float* Wout  = (const float*)d_in[10];
    const float* bout  = (const float*)d_in[11];
    const float* trans = (const float*)d_in[12];
    const float* h0    = (const float*)d_in[13];
    const float* c0    = (const float*)d_in[14];
    const int*   startp= (const int*)  d_in[15];
    const int*   endp  = (const int*)  d_in[16];

    char* ws = (char*)d_ws;
    float* xw   = (float*)(ws + OFF_XW);
    float* hcat = (float*)(ws + OFF_HCAT);
    float* frm  = (float*)(ws + OFF_FRM);
    float* hbuf = (float*)(ws + OFF_HBUF);
    unsigned char* bp = (unsigned char*)(ws + OFF_BP);

    dim3 g1(32, 32, 2);
    k_xw<<<g1, 256, 0, stream>>>(words, embed, WihF, WihB, bihF, bhhF,
                                 bihB, bhhB, xw, hbuf);
    k_lstm<<<dim3(2*NWG), 512, 0, stream>>>(WhhF, WhhB, h0, c0, xw, hbuf, hcat);
    k_frames<<<dim3(TT), 64, 0, stream>>>(hcat, Wout, bout, frm);
    k_viterbi<<<dim3(1), 256, 0, stream>>>(frm, trans, startp, endp, bp, (float*)d_out);
}